// Round 1
// baseline (9363.366 us; speedup 1.0000x reference)
//
#include <hip/hip_runtime.h>
#include <hip/hip_bf16.h>
#include <stdint.h>

// LSTM: T=512, B=64, I=1024, H=1024
// Strategy: bf16 MFMA for gates = [h | x_t] @ [w_hh | w_ih]^T + (b_ih+b_hh),
// fp32 cell state kept in d_out's c region, h double-buffered in bf16 in ws.
// One kernel launch per timestep (stream-ordered dependency).

#define TSTEPS 512
#define BATCH  64
#define HID    1024
#define K2     2048   // I + H
#define G4     4096   // 4*H

typedef short  short8 __attribute__((ext_vector_type(8)));
typedef float  f32x4  __attribute__((ext_vector_type(4)));

__device__ __forceinline__ unsigned short f2bf(float f) {
    uint32_t u = __float_as_uint(f);
    uint32_t r = (u + 0x7fffu + ((u >> 16) & 1u)) >> 16;
    return (unsigned short)r;
}

__device__ __forceinline__ float sigmoidf_fast(float x) {
    return 1.0f / (1.0f + __expf(-x));
}
__device__ __forceinline__ float tanhf_fast(float x) {
    // tanh(x) = 1 - 2/(exp(2x)+1); saturates correctly for |x| large
    return 1.0f - 2.0f / (__expf(2.0f * x) + 1.0f);
}

// ---------------- setup: convert x to bf16 ----------------
__global__ void k_convert_x(const float* __restrict__ x,
                            unsigned short* __restrict__ xb, int n4) {
    int idx = blockIdx.x * blockDim.x + threadIdx.x;
    int stride = gridDim.x * blockDim.x;
    const float4* x4 = (const float4*)x;
    ushort4* o4 = (ushort4*)xb;
    for (int i = idx; i < n4; i += stride) {
        float4 v = x4[i];
        o4[i] = make_ushort4(f2bf(v.x), f2bf(v.y), f2bf(v.z), f2bf(v.w));
    }
}

// ---------------- setup: w_cat (bf16), bias sum, h0 (bf16), c0 copy ----------------
__global__ void k_setup(const float* __restrict__ w_ih, const float* __restrict__ w_hh,
                        const float* __restrict__ b_ih, const float* __restrict__ b_hh,
                        const float* __restrict__ h0,   const float* __restrict__ c0,
                        unsigned short* __restrict__ w_cat, float* __restrict__ bias,
                        unsigned short* __restrict__ hb0,   float* __restrict__ outC) {
    int idx = blockIdx.x * blockDim.x + threadIdx.x;
    int stride = gridDim.x * blockDim.x;

    // w_cat[n][k]: k<1024 -> w_hh[n][k], else w_ih[n][k-1024].  4096*2048 elems, /4 = 2097152 tasks
    ushort4* wc4 = (ushort4*)w_cat;
    for (int i = idx; i < 2097152; i += stride) {
        int nrow = i >> 9;              // 512 float4 tasks per row of 2048
        int kk = (i & 511) << 2;
        const float* src = (kk < 1024) ? (w_hh + (size_t)nrow * 1024 + kk)
                                       : (w_ih + (size_t)nrow * 1024 + (kk - 1024));
        float4 v = *(const float4*)src;
        wc4[i] = make_ushort4(f2bf(v.x), f2bf(v.y), f2bf(v.z), f2bf(v.w));
    }
    // bias = b_ih + b_hh  (4096 -> 1024 float4)
    const float4* bi4 = (const float4*)b_ih;
    const float4* bh4 = (const float4*)b_hh;
    float4* bs4 = (float4*)bias;
    for (int i = idx; i < 1024; i += stride) {
        float4 a = bi4[i], b = bh4[i];
        bs4[i] = make_float4(a.x + b.x, a.y + b.y, a.z + b.z, a.w + b.w);
    }
    // h0 -> bf16 (65536 -> 16384 float4)
    const float4* h04 = (const float4*)h0;
    ushort4* hb4 = (ushort4*)hb0;
    for (int i = idx; i < 16384; i += stride) {
        float4 v = h04[i];
        hb4[i] = make_ushort4(f2bf(v.x), f2bf(v.y), f2bf(v.z), f2bf(v.w));
    }
    // c0 -> outC (fp32 state lives in d_out)
    const float4* c04 = (const float4*)c0;
    float4* oc4 = (float4*)outC;
    for (int i = idx; i < 16384; i += stride) {
        oc4[i] = c04[i];
    }
}

// ---------------- one LSTM timestep ----------------
// grid: (128 j-blocks, 2 batch-halves), 256 threads (4 waves: 2 M-tiles x 2 N-tiles)
// Each wave: one 16x16 MFMA output tile, K=2048 ([h | x_t] vs w_cat).
// Block covers batches bhalf*32..+32, j-columns jblk*8..+8 (x 4 gates = 32 gate cols).
__global__ __launch_bounds__(256) void k_step(
    const unsigned short* __restrict__ h_prev,   // [64][1024] bf16
    unsigned short* __restrict__ h_next,         // [64][1024] bf16
    const unsigned short* __restrict__ xt,       // [64][1024] bf16
    const unsigned short* __restrict__ w_cat,    // [4096][2048] bf16
    const float* __restrict__ bias,              // [4096]
    float* __restrict__ outH, float* __restrict__ outC)  // [64][1024] each
{
    const int lane = threadIdx.x & 63;
    const int w    = threadIdx.x >> 6;   // 0..3
    const int mw   = w >> 1;             // M-tile within batch-half
    const int nw   = w & 1;              // N-tile (j-half of block)
    const int bbase = blockIdx.y * 32 + mw * 16;
    const int j0    = blockIdx.x * 8 + nw * 4;

    const int r  = lane & 15;            // A row / B col selector
    const int kq = lane >> 4;            // 0..3, k-subgroup
    // B col c = r -> gate g = r>>2, j offset = r&3 -> n = g*1024 + j0 + (r&3)
    const int n = ((r >> 2) << 10) + j0 + (r & 3);

    const short8* ah = (const short8*)(h_prev + (size_t)(bbase + r) * HID + kq * 8);
    const short8* ax = (const short8*)(xt     + (size_t)(bbase + r) * HID + kq * 8);
    const short8* bw = (const short8*)(w_cat  + (size_t)n * K2 + kq * 8);

    f32x4 acc0 = {0.f, 0.f, 0.f, 0.f};
    f32x4 acc1 = {0.f, 0.f, 0.f, 0.f};
    #pragma unroll 8
    for (int kit = 0; kit < 32; ++kit) {
        acc0 = __builtin_amdgcn_mfma_f32_16x16x32_bf16(ah[4 * kit], bw[4 * kit], acc0, 0, 0, 0);
    }
    #pragma unroll 8
    for (int kit = 0; kit < 32; ++kit) {
        acc1 = __builtin_amdgcn_mfma_f32_16x16x32_bf16(ax[4 * kit], bw[128 + 4 * kit], acc1, 0, 0, 0);
    }
    f32x4 acc = acc0 + acc1;

    // D layout: col = lane&15 (= our n), row = kq*4 + q (batch within tile)
    const float bn = bias[n];
    __shared__ float lds[4][16][17];
    #pragma unroll
    for (int q = 0; q < 4; ++q) {
        lds[w][kq * 4 + q][r] = acc[q] + bn;
    }
    __syncthreads();

    // Cell update: lane handles (batch row = r, j offset = kq)
    const int b = bbase + r;
    const int j = j0 + kq;
    const int ci = b * HID + j;
    float gi = lds[w][r][0 + kq];
    float gf = lds[w][r][4 + kq];
    float gg = lds[w][r][8 + kq];
    float go = lds[w][r][12 + kq];
    float i_g = sigmoidf_fast(gi);
    float f_g = sigmoidf_fast(gf);
    float g_g = tanhf_fast(gg);
    float o_g = sigmoidf_fast(go);
    float c_new = f_g * outC[ci] + i_g * g_g;
    float h_new = o_g * tanhf_fast(c_new);
    outC[ci] = c_new;
    outH[ci] = h_new;
    h_next[ci] = f2bf(h_new);
}

extern "C" void kernel_launch(void* const* d_in, const int* in_sizes, int n_in,
                              void* d_out, int out_size, void* d_ws, size_t ws_size,
                              hipStream_t stream) {
    const float* x    = (const float*)d_in[0];
    const float* h0   = (const float*)d_in[1];
    const float* c0   = (const float*)d_in[2];
    const float* w_ih = (const float*)d_in[3];
    const float* w_hh = (const float*)d_in[4];
    const float* b_ih = (const float*)d_in[5];
    const float* b_hh = (const float*)d_in[6];

    float* outH = (float*)d_out;           // 65536 floats: final h
    float* outC = outH + 65536;            // 65536 floats: final c (also the live c state)

    uint8_t* ws = (uint8_t*)d_ws;
    unsigned short* xb    = (unsigned short*)ws;                       // 67,108,864 B
    unsigned short* w_cat = (unsigned short*)(ws + 67108864);          // 16,777,216 B
    float*          bias  = (float*)(ws + 67108864 + 16777216);       // 16,384 B
    unsigned short* hb0   = (unsigned short*)(ws + 83902464);          // 131,072 B
    unsigned short* hb1   = hb0 + 65536;                               // 131,072 B

    k_convert_x<<<4096, 256, 0, stream>>>(x, xb, 8388608);
    k_setup<<<2048, 256, 0, stream>>>(w_ih, w_hh, b_ih, b_hh, h0, c0,
                                      w_cat, bias, hb0, outC);

    unsigned short* hp = hb0;
    unsigned short* hn = hb1;
    for (int t = 0; t < TSTEPS; ++t) {
        k_step<<<dim3(128, 2), 256, 0, stream>>>(hp, hn,
                                                 xb + (size_t)t * BATCH * HID,
                                                 w_cat, bias, outH, outC);
        unsigned short* tmp = hp; hp = hn; hn = tmp;
    }
}